// Round 1
// baseline (570.937 us; speedup 1.0000x reference)
//
#include <hip/hip_runtime.h>
#include <type_traits>

namespace {
constexpr int HH = 512;
constexpr int WW = 512;
constexpr int KS = 11;
constexpr int PADR = 5;
constexpr int BH = 32;               // output rows per block (band)
constexpr int VR = 8;                // output rows per phase-1 round
constexpr int SR = 4;                // rows staged per phase-2 sub-step
constexpr int LP = 525;              // LDS pitch: 525 mod 32 = 13 -> phase-2
                                     // lane banks 13*row+4*m cover all 32 banks
                                     // exactly 2-way (free) -- same verified
                                     // pattern as the previous kernel
constexpr int NTHREADS = 256;
constexpr float SSIM_C1 = 1.0e-4f;   // (0.01*1.0)^2
constexpr float SSIM_C2 = 9.0e-4f;   // (0.03*1.0)^2
}

// Full-width band kernel. Each block owns a 32-row x 512-col band of one plane.
//  - Phase 1 (vertical 11-tap): 256 threads x 2 adjacent columns (float2
//    loads, 512B/wave contiguous). V=8 output rows accumulated per round from
//    18 streamed input rows: products x^2,y^2,xy computed ONCE per input
//    pixel, FMA'd into <=8 alive accumulators with compile-time weights.
//    This replaces 22 loads + 88 VALU per vertical position with
//    2.25 loads + ~65 VALU per output.
//  - No horizontal halo recompute: block covers the full row; image borders
//    are zero pads written once into LDS columns [0,5) and [517,525).
//  - Phase 2 (horizontal 11-tap + SSIM): unchanged structure, 4 rows x 16
//    col-groups per wave, two 256-col passes, pitch-525 bank-free reads.
__global__ __launch_bounds__(NTHREADS, 3) void ssim_fused(
    const float* __restrict__ x, const float* __restrict__ y,
    const float* __restrict__ kern, float* __restrict__ out)
{
    __shared__ float vb[5][SR][LP];   // 42000 B -> 3 blocks/CU

    const int bid = blockIdx.x;
    const int plane = bid >> 4;          // 16 bands per plane
    const int band  = bid & 15;
    const int tile_r = band * BH;

    const float* __restrict__ xp = x + (size_t)plane * (HH * WW);
    const float* __restrict__ yp = y + (size_t)plane * (HH * WW);
    float* __restrict__ op = out + (size_t)plane * (HH * WW);

    // 1D gaussian from the 2D kernel (exact for outer products)
    float wt[KS];
    {
        const float c = kern[5 * KS + 5];
        const float inv = rsqrtf(c);
#pragma unroll
        for (int i = 0; i < KS; ++i) wt[i] = kern[5 * KS + i] * inv;
    }

    const int t = threadIdx.x;
    const int c0 = 2 * t;                // this thread's input columns c0, c0+1

    // zero the horizontal pad columns once: [0,PADR) and [WW+PADR, LP)
    {
        constexpr int PADL = PADR;               // 5
        constexpr int PADRW = LP - (WW + PADR);  // 8
        constexpr int PPR = PADL + PADRW;        // 13 pad floats per (stat,row)
        for (int i = t; i < 5 * SR * PPR; i += NTHREADS) {
            const int q = i / PPR;
            const int rm = i - q * PPR;
            const int col = (rm < PADL) ? rm : (WW + PADR + rm - PADL);
            (&vb[0][0][0])[q * LP + col] = 0.f;
        }
    }
    __syncthreads();

    const bool interior = (tile_r >= PADR) && (tile_r + BH + PADR <= HH);

    const int prow = (t >> 4) & 3;                 // phase-2 row 0..3
    const int pcg  = (t & 15) | ((t >> 6) << 4);   // phase-2 col group 0..63

    auto run_round = [&](int r0, auto intr_tag) {
        constexpr bool INTR = decltype(intr_tag)::value;

        // ---- phase 1: vertical blur, V=8 rows, products computed once
        float2 acc[5][VR];
#pragma unroll
        for (int s = 0; s < 5; ++s)
#pragma unroll
            for (int o = 0; o < VR; ++o) acc[s][o] = make_float2(0.f, 0.f);

        const float* xq = xp + (ptrdiff_t)(r0 - PADR) * WW + c0;
        const float* yq = yp + (ptrdiff_t)(r0 - PADR) * WW + c0;
#pragma unroll
        for (int k = 0; k < VR + 2 * PADR; ++k) {   // 18 input rows
            float2 xv, yv;
            if (INTR) {
                xv = *(const float2*)(xq + (ptrdiff_t)k * WW);
                yv = *(const float2*)(yq + (ptrdiff_t)k * WW);
            } else {
                const int rr = r0 - PADR + k;
                if (rr >= 0 && rr < HH) {
                    xv = *(const float2*)(xq + (ptrdiff_t)k * WW);
                    yv = *(const float2*)(yq + (ptrdiff_t)k * WW);
                } else {
                    xv = make_float2(0.f, 0.f);
                    yv = make_float2(0.f, 0.f);
                }
            }
            const float xx0 = xv.x * xv.x, xx1 = xv.y * xv.y;
            const float yy0 = yv.x * yv.x, yy1 = yv.y * yv.y;
            const float xy0 = xv.x * yv.x, xy1 = xv.y * yv.y;
#pragma unroll
            for (int o = 0; o < VR; ++o) {
                constexpr int dummy = 0; (void)dummy;
                const int j = k - o;                 // compile-time after unroll
                if (j >= 0 && j < KS) {
                    const float w = wt[j];
                    acc[0][o].x += w * xv.x;  acc[0][o].y += w * xv.y;
                    acc[1][o].x += w * yv.x;  acc[1][o].y += w * yv.y;
                    acc[2][o].x += w * xx0;   acc[2][o].y += w * xx1;
                    acc[3][o].x += w * yy0;   acc[3][o].y += w * yy1;
                    acc[4][o].x += w * xy0;   acc[4][o].y += w * xy1;
                }
            }
        }

        // ---- two sub-steps: stage 4 rows -> phase 2 -> repeat
#pragma unroll
        for (int sub = 0; sub < 2; ++sub) {
#pragma unroll
            for (int rr = 0; rr < SR; ++rr) {
#pragma unroll
                for (int s = 0; s < 5; ++s) {
                    vb[s][rr][c0 + PADR]     = acc[s][sub * SR + rr].x;
                    vb[s][rr][c0 + PADR + 1] = acc[s][sub * SR + rr].y;
                }
            }
            __syncthreads();

#pragma unroll
            for (int pass = 0; pass < 2; ++pass) {
                const int ocol = (pcg + (pass << 6)) << 2;   // 0..508
                float res[5][4];
#pragma unroll
                for (int s = 0; s < 5; ++s) {
                    float wnd[KS + 3];
#pragma unroll
                    for (int i2 = 0; i2 < KS + 3; ++i2)
                        wnd[i2] = vb[s][prow][ocol + i2];
#pragma unroll
                    for (int jj = 0; jj < 4; ++jj) {
                        float a = 0.f;
#pragma unroll
                        for (int k = 0; k < KS; ++k) a += wt[k] * wnd[jj + k];
                        res[s][jj] = a;
                    }
                }
                float4 o4;
#pragma unroll
                for (int jj = 0; jj < 4; ++jj) {
                    const float ux = res[0][jj], uy = res[1][jj];
                    const float uxx = res[2][jj], uyy = res[3][jj], uxy = res[4][jj];
                    const float vx  = uxx - ux * ux;
                    const float vy  = uyy - uy * uy;
                    const float vxy = uxy - ux * uy;
                    const float a1 = 2.f * ux * uy + SSIM_C1;
                    const float a2 = 2.f * vxy + SSIM_C2;
                    const float b1 = ux * ux + uy * uy + SSIM_C1;
                    const float b2 = vx + vy + SSIM_C2;
                    (&o4.x)[jj] = (a1 * a2) * __builtin_amdgcn_rcpf(b1 * b2);
                }
                *(float4*)(op + (size_t)(r0 + sub * SR + prow) * WW + ocol) = o4;
            }
            __syncthreads();   // LDS reused by next sub-step / round
        }
    };

    if (interior) {
        for (int j = 0; j < BH / VR; ++j)
            run_round(tile_r + j * VR, std::true_type{});
    } else {
        for (int j = 0; j < BH / VR; ++j)
            run_round(tile_r + j * VR, std::false_type{});
    }
}

extern "C" void kernel_launch(void* const* d_in, const int* in_sizes, int n_in,
                              void* d_out, int out_size, void* d_ws, size_t ws_size,
                              hipStream_t stream) {
    const float* x    = (const float*)d_in[0];
    const float* y    = (const float*)d_in[1];
    const float* kern = (const float*)d_in[2];
    float* out = (float*)d_out;

    const int nplanes = in_sizes[0] / (HH * WW);        // 48
    const int nblocks = nplanes * (HH / BH);            // 48 * 16 = 768

    ssim_fused<<<dim3(nblocks), dim3(NTHREADS), 0, stream>>>(x, y, kern, out);
}

// Round 2
// 253.231 us; speedup vs baseline: 2.2546x; 2.2546x over previous
//
#include <hip/hip_runtime.h>
#include <type_traits>

namespace {
constexpr int HH = 512;
constexpr int WW = 512;
constexpr int KS = 11;
constexpr int PADR = 5;
constexpr int BH = 32;               // output rows per block (band)
constexpr int VR = 4;                // output rows per round (= rows staged)
constexpr int LP = 525;              // LDS pitch: 525 mod 32 = 13 -> phase-2
                                     // lane banks 13*row + 4*m + i2 split into
                                     // 4 cosets mod 4 -> all 32 banks exactly
                                     // 2-way (free; verified pattern)
constexpr int NTHREADS = 256;
constexpr float SSIM_C1 = 1.0e-4f;   // (0.01*1.0)^2
constexpr float SSIM_C2 = 9.0e-4f;   // (0.03*1.0)^2
}

// Full-width band kernel, spill-proofed phase 1.
//  - Each block owns a 32-row x 512-col band. 256 threads x 2 adjacent
//    columns (float2 global loads -> 512B/wave contiguous).
//  - Phase 1 (vertical 11-tap): stream 14 input rows per round, compute
//    x^2,y^2,xy ONCE per input pixel, FMA into 4 output-row accumulators.
//    Accumulators are PLAIN float arrays with all-constant indices (the R1
//    float2 acc[5][8] was never SROA-promoted -> 650 MB scratch traffic,
//    WRITE_SIZE 702 MB, VALUBusy 9%). 40 floats, dead before phase 2.
//  - No horizontal halo recompute: image borders are zero pads in LDS.
//  - Phase 2 (horizontal 11-tap + SSIM): 4 rows x 16 col-groups per wave,
//    two 256-col passes, pitch-525 bank-free reads, float4 stores.
__global__ __launch_bounds__(NTHREADS, 3) void ssim_fused(
    const float* __restrict__ x, const float* __restrict__ y,
    const float* __restrict__ kern, float* __restrict__ out)
{
    __shared__ float vb[5][VR][LP];   // 42000 B -> 3 blocks/CU (LDS-capped)

    const int bid = blockIdx.x;
    const int plane = bid >> 4;          // 16 bands per plane
    const int band  = bid & 15;
    const int tile_r = band * BH;

    const float* __restrict__ xp = x + (size_t)plane * (HH * WW);
    const float* __restrict__ yp = y + (size_t)plane * (HH * WW);
    float* __restrict__ op = out + (size_t)plane * (HH * WW);

    // 1D gaussian from the 2D kernel (exact for outer products)
    float wt[KS];
    {
        const float c = kern[5 * KS + 5];
        const float inv = rsqrtf(c);
#pragma unroll
        for (int i = 0; i < KS; ++i) wt[i] = kern[5 * KS + i] * inv;
    }

    const int t = threadIdx.x;
    const int c0 = 2 * t;                // this thread's input columns

    // zero the horizontal pad columns once: [0,PADR) and [WW+PADR, LP)
    {
        constexpr int PPR = PADR + (LP - (WW + PADR));   // 5 + 8 = 13
        for (int i = t; i < 5 * VR * PPR; i += NTHREADS) {
            const int q = i / PPR;
            const int rm = i - q * PPR;
            const int col = (rm < PADR) ? rm : (WW + PADR + rm - PADR);
            (&vb[0][0][0])[q * LP + col] = 0.f;
        }
    }
    __syncthreads();

    const bool interior = (tile_r >= PADR) && (tile_r + BH + PADR <= HH);

    const int prow = (t >> 4) & 3;                 // phase-2 row 0..3
    const int pcg  = (t & 15) | ((t >> 6) << 4);   // phase-2 col group 0..63

    auto run_round = [&](int r0, auto intr_tag) {
        constexpr bool INTR = decltype(intr_tag)::value;

        // ---- phase 1: vertical blur, VR rows, products computed once.
        // Plain float arrays, every index a compile-time constant.
        float a0[VR][2], a1[VR][2], a2[VR][2], a3[VR][2], a4[VR][2];
#pragma unroll
        for (int o = 0; o < VR; ++o) {
            a0[o][0] = 0.f; a0[o][1] = 0.f;
            a1[o][0] = 0.f; a1[o][1] = 0.f;
            a2[o][0] = 0.f; a2[o][1] = 0.f;
            a3[o][0] = 0.f; a3[o][1] = 0.f;
            a4[o][0] = 0.f; a4[o][1] = 0.f;
        }

        const float* xq = xp + (ptrdiff_t)(r0 - PADR) * WW + c0;
        const float* yq = yp + (ptrdiff_t)(r0 - PADR) * WW + c0;
#pragma unroll
        for (int k = 0; k < VR + 2 * PADR; ++k) {   // 14 input rows
            float xv0, xv1, yv0, yv1;
            if (INTR) {
                const float2 xv = *(const float2*)(xq + (ptrdiff_t)k * WW);
                const float2 yv = *(const float2*)(yq + (ptrdiff_t)k * WW);
                xv0 = xv.x; xv1 = xv.y; yv0 = yv.x; yv1 = yv.y;
            } else {
                const int rr = r0 - PADR + k;
                if (rr >= 0 && rr < HH) {
                    const float2 xv = *(const float2*)(xq + (ptrdiff_t)k * WW);
                    const float2 yv = *(const float2*)(yq + (ptrdiff_t)k * WW);
                    xv0 = xv.x; xv1 = xv.y; yv0 = yv.x; yv1 = yv.y;
                } else {
                    xv0 = 0.f; xv1 = 0.f; yv0 = 0.f; yv1 = 0.f;
                }
            }
            const float xx0 = xv0 * xv0, xx1 = xv1 * xv1;
            const float yy0 = yv0 * yv0, yy1 = yv1 * yv1;
            const float xy0 = xv0 * yv0, xy1 = xv1 * yv1;
#pragma unroll
            for (int o = 0; o < VR; ++o) {
                const int j = k - o;                 // constant after unroll
                if (j >= 0 && j < KS) {
                    const float w = wt[j];
                    a0[o][0] += w * xv0;  a0[o][1] += w * xv1;
                    a1[o][0] += w * yv0;  a1[o][1] += w * yv1;
                    a2[o][0] += w * xx0;  a2[o][1] += w * xx1;
                    a3[o][0] += w * yy0;  a3[o][1] += w * yy1;
                    a4[o][0] += w * xy0;  a4[o][1] += w * xy1;
                }
            }
        }

        // ---- stage VR rows into LDS (scalar writes: addr 2t+const is only
        // 4B-aligned; lanes stride-2 floats -> 2-way banks, free)
#pragma unroll
        for (int o = 0; o < VR; ++o) {
            vb[0][o][PADR + c0]     = a0[o][0];
            vb[0][o][PADR + c0 + 1] = a0[o][1];
            vb[1][o][PADR + c0]     = a1[o][0];
            vb[1][o][PADR + c0 + 1] = a1[o][1];
            vb[2][o][PADR + c0]     = a2[o][0];
            vb[2][o][PADR + c0 + 1] = a2[o][1];
            vb[3][o][PADR + c0]     = a3[o][0];
            vb[3][o][PADR + c0 + 1] = a3[o][1];
            vb[4][o][PADR + c0]     = a4[o][0];
            vb[4][o][PADR + c0 + 1] = a4[o][1];
        }
        __syncthreads();

        // ---- phase 2: horizontal 11-tap blur + SSIM, 4 outputs x 2 passes
#pragma unroll
        for (int pass = 0; pass < 2; ++pass) {
            const int ocol = (pcg + (pass << 6)) << 2;   // 0..508
            float res[5][4];
#pragma unroll
            for (int s = 0; s < 5; ++s) {
                float wnd[KS + 3];
#pragma unroll
                for (int i2 = 0; i2 < KS + 3; ++i2)
                    wnd[i2] = vb[s][prow][ocol + i2];
#pragma unroll
                for (int jj = 0; jj < 4; ++jj) {
                    float a = 0.f;
#pragma unroll
                    for (int k = 0; k < KS; ++k) a += wt[k] * wnd[jj + k];
                    res[s][jj] = a;
                }
            }
            float4 o4;
#pragma unroll
            for (int jj = 0; jj < 4; ++jj) {
                const float ux = res[0][jj], uy = res[1][jj];
                const float uxx = res[2][jj], uyy = res[3][jj], uxy = res[4][jj];
                const float vx  = uxx - ux * ux;
                const float vy  = uyy - uy * uy;
                const float vxy = uxy - ux * uy;
                const float A1 = 2.f * ux * uy + SSIM_C1;
                const float A2 = 2.f * vxy + SSIM_C2;
                const float B1 = ux * ux + uy * uy + SSIM_C1;
                const float B2 = vx + vy + SSIM_C2;
                (&o4.x)[jj] = (A1 * A2) * __builtin_amdgcn_rcpf(B1 * B2);
            }
            *(float4*)(op + (size_t)(r0 + prow) * WW + ocol) = o4;
        }
        __syncthreads();   // LDS reused by next round
    };

    if (interior) {
        for (int j = 0; j < BH / VR; ++j)
            run_round(tile_r + j * VR, std::true_type{});
    } else {
        for (int j = 0; j < BH / VR; ++j)
            run_round(tile_r + j * VR, std::false_type{});
    }
}

extern "C" void kernel_launch(void* const* d_in, const int* in_sizes, int n_in,
                              void* d_out, int out_size, void* d_ws, size_t ws_size,
                              hipStream_t stream) {
    const float* x    = (const float*)d_in[0];
    const float* y    = (const float*)d_in[1];
    const float* kern = (const float*)d_in[2];
    float* out = (float*)d_out;

    const int nplanes = in_sizes[0] / (HH * WW);        // 48
    const int nblocks = nplanes * (HH / BH);            // 48 * 16 = 768

    ssim_fused<<<dim3(nblocks), dim3(NTHREADS), 0, stream>>>(x, y, kern, out);
}